// Round 5
// baseline (77.695 us; speedup 1.0000x reference)
//
#include <hip/hip_runtime.h>
#include <math.h>

// S4D SSM kernel materialization:
//   K[h,l] = 2 * Re( sum_n CB[h,n] * exp(dtA[h,n] * l) ) + D[h]*(l==0)
//
// R5 strategy (assumes L = 1024, N = 64 per the problem spec):
//  - block = 512 (8 waves), one h per block. Wave w owns states [8w, 8w+8)
//    (4 even pairs, <2 x float> SoA). Each lane owns T=16 consecutive l.
//    Halves per-item setup cost (trans + wave-uniform LDS const reads +
//    CB*z0) vs R4's 16-states/wave split; rotation work unchanged (it is
//    the algorithmic floor, ~2.1 us chip-wide).
//  - z0 = exp(dtA*l0) once per (pair, lane); 15-step complex-rotation
//    recurrence (step = exp(dtA)) generates the chunk — no trans inside.
//  - Cross-wave reduction via 32 KB LDS partials, interleaved layout
//    pos(l) = (l&15)*64 + (l>>4): partial writes are lane-consecutive
//    (conflict-free); one-shot reduction reads negligible.
//  - Final *2 folded into CB at setup.

#define NSTATE 64
#define TCHUNK 16
#define NWAVE  8

typedef float v2f __attribute__((ext_vector_type(2)));

__global__ __launch_bounds__(512) void ssk_diag_kernel(
    const float* __restrict__ log_dt,   // (H,)
    const float* __restrict__ Lre,      // (H,N)
    const float* __restrict__ Lim,      // (H,N)
    const float* __restrict__ Bv,       // (H,N,1)
    const float* __restrict__ Cre,      // (H,1,N)
    const float* __restrict__ Cim,      // (H,1,N)
    const float* __restrict__ Dv,       // (H,)
    float* __restrict__ K,              // (H,L)
    int L)
{
    const int h   = blockIdx.x;
    const int tid = threadIdx.x;

    // SoA so even-n pairs are contiguous for v2f loads
    __shared__ float s_are[NSTATE], s_aim[NSTATE];
    __shared__ float s_str[NSTATE], s_sti[NSTATE];   // step = exp(dtA)
    __shared__ float s_cbr[NSTATE], s_cbi[NSTATE];   // 2*CB
    __shared__ float s_part[NWAVE * 1024];           // per-wave partials, 32 KB

    if (tid < NSTATE) {
        const int n   = tid;
        const int idx = h * NSTATE + n;
        const float dt  = expf(log_dt[h]);
        const float lre = Lre[idx];
        const float lim = Lim[idx];
        const float are = dt * lre;
        const float aim = dt * lim;

        // Stable complex expm1: exp(are+i*aim) - 1
        float sy, cy;
        sincosf(aim, &sy, &cy);
        const float sh    = sinf(0.5f * aim);
        const float em_re = expm1f(are) * cy - 2.0f * sh * sh;
        const float em_im = expf(are) * sy;

        // B_bar = em / Lambda * B
        const float inv_d = 1.0f / (lre * lre + lim * lim);
        const float b     = Bv[idx];
        const float bb_re = (em_re * lre + em_im * lim) * inv_d * b;
        const float bb_im = (em_im * lre - em_re * lim) * inv_d * b;

        // 2*CB = 2 * (Cre + i*Cim) * B_bar   (fold the final *2 in here)
        const float cre = Cre[idx];
        const float cim = Cim[idx];
        s_cbr[n] = 2.0f * (cre * bb_re - cim * bb_im);
        s_cbi[n] = 2.0f * (cre * bb_im + cim * bb_re);
        s_are[n] = are;
        s_aim[n] = aim;
        s_str[n] = em_re + 1.0f;   // exp(dtA) = expm1(dtA) + 1
        s_sti[n] = em_im;
    }
    __syncthreads();

    const int wave = tid >> 6;
    const int lane = tid & 63;
    const int l0   = lane * TCHUNK;
    const float fl = (float)l0;

    v2f acc[TCHUNK];
    #pragma unroll
    for (int t = 0; t < TCHUNK; ++t) acc[t] = (v2f){0.0f, 0.0f};

    const int nb = wave * 8;   // this wave's 8 states = 4 even pairs
    #pragma unroll
    for (int p = 0; p < 4; ++p) {
        const int n = nb + 2 * p;
        const v2f ar  = *(const v2f*)&s_are[n];
        const v2f ai  = *(const v2f*)&s_aim[n];
        const v2f str_= *(const v2f*)&s_str[n];
        const v2f sti = *(const v2f*)&s_sti[n];
        const v2f cbr = *(const v2f*)&s_cbr[n];
        const v2f cbi = *(const v2f*)&s_cbi[n];

        // z0 = exp(dtA * l0)
        const v2f argr = ar * fl;
        const v2f argi = ai * fl;
        const float m0 = __expf(argr.x);
        const float m1 = __expf(argr.y);
        float s0, c0, s1, c1;
        __sincosf(argi.x, &s0, &c0);
        __sincosf(argi.y, &s1, &c1);
        const v2f zr = {m0 * c0, m1 * c1};
        const v2f zi = {m0 * s0, m1 * s1};

        // w = (2*CB) * z0
        v2f wr = cbr * zr - cbi * zi;
        v2f wi = cbr * zi + cbi * zr;

        #pragma unroll
        for (int t = 0; t < TCHUNK; ++t) {
            acc[t] += wr;
            if (t < TCHUNK - 1) {
                const v2f nr = wr * str_ - wi * sti;
                wi = wr * sti + wi * str_;
                wr = nr;
            }
        }
    }

    // Write per-wave partials, interleaved: pos(l) = (l&15)*64 + (l>>4).
    // For this thread, l = l0 + t -> pos = t*64 + lane (lane-consecutive).
    {
        float* base = &s_part[wave * 1024];
        #pragma unroll
        for (int t = 0; t < TCHUNK; ++t)
            base[t * 64 + lane] = acc[t].x + acc[t].y;
    }
    __syncthreads();

    // Reduce 8 waves' partials; thread tid produces l = 2*tid, 2*tid+1.
    float2 o;
    float* op = &o.x;
    #pragma unroll
    for (int k = 0; k < 2; ++k) {
        const int l   = 2 * tid + k;
        const int pos = (l & 15) * 64 + (l >> 4);
        float s = 0.0f;
        #pragma unroll
        for (int w = 0; w < NWAVE; ++w)
            s += s_part[w * 1024 + pos];
        op[k] = s;
    }
    if (tid == 0) o.x += Dv[h];
    *(float2*)(K + h * L + tid * 2) = o;
}

extern "C" void kernel_launch(void* const* d_in, const int* in_sizes, int n_in,
                              void* d_out, int out_size, void* d_ws, size_t ws_size,
                              hipStream_t stream) {
    const float* log_dt = (const float*)d_in[0];
    const float* Lre    = (const float*)d_in[1];
    const float* Lim    = (const float*)d_in[2];
    const float* B      = (const float*)d_in[3];
    const float* Cre    = (const float*)d_in[4];
    const float* Cim    = (const float*)d_in[5];
    const float* D      = (const float*)d_in[6];
    const int H = in_sizes[0];
    const int L = out_size / H;   // 1024 per problem spec (kernel assumes this)
    float* K = (float*)d_out;

    ssk_diag_kernel<<<H, 512, 0, stream>>>(log_dt, Lre, Lim, B, Cre, Cim, D, K, L);
}

// Round 6
// 76.862 us; speedup vs baseline: 1.0108x; 1.0108x over previous
//
#include <hip/hip_runtime.h>
#include <math.h>

// S4D SSM kernel materialization:
//   K[h,l] = 2 * Re( sum_n CB[h,n] * exp(dtA[h,n] * l) ) + D[h]*(l==0)
//
// R6 = revert to R4 (measured best: 75.7 us vs R5's 77.7 us).
// R5 post-mortem: 8-wave split halved per-wave setup but doubled the
// cross-wave reduction (32 KB partials, 8-way read-sum, 512-thread barrier)
// — net regression. R4's 4 waves x 16 states is the setup/reduction optimum.
//
// Structure (assumes L = 1024, N = 64 per the problem spec):
//  - block = 256 (4 waves), one h per block. Wave w owns states [16w,16w+16)
//    (8 even pairs, <2 x float> SoA). Each lane owns T=16 consecutive l.
//  - z0 = exp(dtA*l0) once per (pair, lane) with fast trans; 15-step
//    complex-rotation recurrence (step = exp(dtA)) generates the chunk —
//    no transcendentals in the inner loop.
//  - Cross-wave reduction via 16 KB LDS partials, interleaved layout
//    pos(l) = (l&15)*64 + (l>>4): partial writes lane-consecutive
//    (conflict-free); one-shot reduction reads negligible.
//  - Final *2 folded into CB at setup.

#define NSTATE 64
#define TCHUNK 16

typedef float v2f __attribute__((ext_vector_type(2)));

__global__ __launch_bounds__(256) void ssk_diag_kernel(
    const float* __restrict__ log_dt,   // (H,)
    const float* __restrict__ Lre,      // (H,N)
    const float* __restrict__ Lim,      // (H,N)
    const float* __restrict__ Bv,       // (H,N,1)
    const float* __restrict__ Cre,      // (H,1,N)
    const float* __restrict__ Cim,      // (H,1,N)
    const float* __restrict__ Dv,       // (H,)
    float* __restrict__ K,              // (H,L)
    int L)
{
    const int h   = blockIdx.x;
    const int tid = threadIdx.x;

    // SoA so even-n pairs are contiguous for v2f loads
    __shared__ float s_are[NSTATE], s_aim[NSTATE];
    __shared__ float s_str[NSTATE], s_sti[NSTATE];   // step = exp(dtA)
    __shared__ float s_cbr[NSTATE], s_cbi[NSTATE];   // 2*CB
    __shared__ float s_part[4 * 1024];               // per-wave partials, 16 KB

    if (tid < NSTATE) {
        const int n   = tid;
        const int idx = h * NSTATE + n;
        const float dt  = expf(log_dt[h]);
        const float lre = Lre[idx];
        const float lim = Lim[idx];
        const float are = dt * lre;
        const float aim = dt * lim;

        // Stable complex expm1: exp(are+i*aim) - 1
        float sy, cy;
        sincosf(aim, &sy, &cy);
        const float sh    = sinf(0.5f * aim);
        const float em_re = expm1f(are) * cy - 2.0f * sh * sh;
        const float em_im = expf(are) * sy;

        // B_bar = em / Lambda * B
        const float inv_d = 1.0f / (lre * lre + lim * lim);
        const float b     = Bv[idx];
        const float bb_re = (em_re * lre + em_im * lim) * inv_d * b;
        const float bb_im = (em_im * lre - em_re * lim) * inv_d * b;

        // 2*CB = 2 * (Cre + i*Cim) * B_bar   (fold the final *2 in here)
        const float cre = Cre[idx];
        const float cim = Cim[idx];
        s_cbr[n] = 2.0f * (cre * bb_re - cim * bb_im);
        s_cbi[n] = 2.0f * (cre * bb_im + cim * bb_re);
        s_are[n] = are;
        s_aim[n] = aim;
        s_str[n] = em_re + 1.0f;   // exp(dtA) = expm1(dtA) + 1
        s_sti[n] = em_im;
    }
    __syncthreads();

    const int wave = tid >> 6;
    const int lane = tid & 63;
    const int l0   = lane * TCHUNK;
    const float fl = (float)l0;

    v2f acc[TCHUNK];
    #pragma unroll
    for (int t = 0; t < TCHUNK; ++t) acc[t] = (v2f){0.0f, 0.0f};

    const int nb = wave * 16;   // this wave's 16 states = 8 even pairs
    #pragma unroll
    for (int p = 0; p < 8; ++p) {
        const int n = nb + 2 * p;
        const v2f ar  = *(const v2f*)&s_are[n];
        const v2f ai  = *(const v2f*)&s_aim[n];
        const v2f str_= *(const v2f*)&s_str[n];
        const v2f sti = *(const v2f*)&s_sti[n];
        const v2f cbr = *(const v2f*)&s_cbr[n];
        const v2f cbi = *(const v2f*)&s_cbi[n];

        // z0 = exp(dtA * l0)
        const v2f argr = ar * fl;
        const v2f argi = ai * fl;
        const float m0 = __expf(argr.x);
        const float m1 = __expf(argr.y);
        float s0, c0, s1, c1;
        __sincosf(argi.x, &s0, &c0);
        __sincosf(argi.y, &s1, &c1);
        const v2f zr = {m0 * c0, m1 * c1};
        const v2f zi = {m0 * s0, m1 * s1};

        // w = (2*CB) * z0
        v2f wr = cbr * zr - cbi * zi;
        v2f wi = cbr * zi + cbi * zr;

        #pragma unroll
        for (int t = 0; t < TCHUNK; ++t) {
            acc[t] += wr;
            if (t < TCHUNK - 1) {
                const v2f nr = wr * str_ - wi * sti;
                wi = wr * sti + wi * str_;
                wr = nr;
            }
        }
    }

    // Write per-wave partials, interleaved: pos(l) = (l&15)*64 + (l>>4).
    // For this thread, l = l0 + t -> pos = t*64 + lane (lane-consecutive).
    {
        float* base = &s_part[wave * 1024];
        #pragma unroll
        for (int t = 0; t < TCHUNK; ++t)
            base[t * 64 + lane] = acc[t].x + acc[t].y;
    }
    __syncthreads();

    // Reduce 4 waves' partials; thread tid produces l = 4*tid .. 4*tid+3.
    const int sub = tid & 3;
    const int blk = tid >> 2;
    float4 o;
    float* op = &o.x;
    #pragma unroll
    for (int k = 0; k < 4; ++k) {
        const int pos = (4 * sub + k) * 64 + blk;
        op[k] = s_part[pos] + s_part[1024 + pos] +
                s_part[2048 + pos] + s_part[3072 + pos];
    }
    if (tid == 0) o.x += Dv[h];
    *(float4*)(K + h * L + tid * 4) = o;
}

extern "C" void kernel_launch(void* const* d_in, const int* in_sizes, int n_in,
                              void* d_out, int out_size, void* d_ws, size_t ws_size,
                              hipStream_t stream) {
    const float* log_dt = (const float*)d_in[0];
    const float* Lre    = (const float*)d_in[1];
    const float* Lim    = (const float*)d_in[2];
    const float* B      = (const float*)d_in[3];
    const float* Cre    = (const float*)d_in[4];
    const float* Cim    = (const float*)d_in[5];
    const float* D      = (const float*)d_in[6];
    const int H = in_sizes[0];
    const int L = out_size / H;   // 1024 per problem spec (kernel assumes this)
    float* K = (float*)d_out;

    ssk_diag_kernel<<<H, 256, 0, stream>>>(log_dt, Lre, Lim, B, Cre, Cim, D, K, L);
}